// Round 16
// baseline (123.153 us; speedup 1.0000x reference)
//
#include <hip/hip_runtime.h>

#define FDIM 64
#define EPB  1024    // edges per block for coarse (grid = 1024 -> 4 blocks/CU)
#define BCAP 6144    // fixed bucket capacity: mean 4096, sd 64 -> +32 sd margin

typedef float nf4 __attribute__((ext_vector_type(4)));
typedef float nf2 __attribute__((ext_vector_type(2)));

// ---- bf16 helpers (manual, RNE) ----
__device__ __forceinline__ unsigned f2bf(float f) {
    unsigned u = __float_as_uint(f);
    u += 0x7fffu + ((u >> 16) & 1u);
    return u >> 16;
}
__device__ __forceinline__ float bflo(unsigned u) { return __uint_as_float(u << 16); }
__device__ __forceinline__ float bfhi(unsigned u) { return __uint_as_float(u & 0xffff0000u); }

// accumulate one gathered uint4 (8 bf16) into 4 packed-f32 pairs
#define ACC4(v) \
    p0 += (nf2){bflo((v).x), bfhi((v).x)}; p1 += (nf2){bflo((v).y), bfhi((v).y)}; \
    p2 += (nf2){bflo((v).z), bfhi((v).z)}; p3 += (nf2){bflo((v).w), bfhi((v).w)};

// ======== GEMM1 + cursor zeroing: HSb1 = bf16( (X @ W1) * dis0[row] ) ========
// NOTE: gemm1 runs BEFORE the CSR build now, so it cannot use dis[] yet.
// Instead it writes the UNSCALED bf16 h1; the dis scaling moves into the
// consumers? -- NO: dis is needed at write time. Solution: gemm1 is
// independent of CSR ONLY if we keep the dis scaling out of it.
// We keep HSb1 = bf16(x@W1) UNSCALED and fold dis[src] into the gather
// consumers? That would add a per-edge multiply. Cheaper: keep order
// coarse->fine->gemm1 and fold the zeroing into... coarse needs zeroed
// cursors FIRST. So: zeroing block rides on k_gemm64s? gemm1 would then
// run first WITHOUT dis. Resolution: scale by dis in k_aggemm/k_agg via
// the ALREADY-loaded dis[row] (norm = dis[s]*dis[d]; we pre-scale rows by
// dis at PRODUCER in old scheme). New scheme: HSb1 holds bf16(h1*1) and
// consumers multiply each gathered row by dis[s]? -> per-edge scalar mul.
// AVOIDED: instead zeroing rides on gemm1 but gemm1 still runs AFTER fine
// (order: coarse needs cursors zeroed at entry). We zero cursors in a tiny
// FIRST block of k_coarse itself using a device-side guard: NOT possible
// without grid sync. FINAL CHOICE (implemented): keep the R15 order and
// simply zero cursorG inside k_fine for the NEXT call? Forbidden (state).
// => We keep the memset but merge gemm1's dispatch slot differently:
// gemm1 rides as extra blocks of k_coarse (blocks >= nbk do gemm tiles,
// using dis=?) -- gemm needs dis. DEAD END chain resolved below by moving
// the dis SCALING to the LDS-write/epilogue of the consumers using
// dis[row] only (norm decomposition: out needs sum over s of h[s]*dis[s],
// all scaled by dis[row]; pre-scaling by dis[src] at producer is what
// requires CSR-before-gemm. Per-edge dis[s] lookup = 1 extra dword gather
// per edge = +25% index traffic. Too costly.)
// CONCLUSION: zeroing stays fused with gemm1 (which DOES run after fine,
// order unchanged from R15); we only DROP the separate memset dispatch by
// zeroing cursorG inside k_gemm64s's extra block -- but cursorG must be
// zero BEFORE k_coarse which precedes gemm1... so instead the extra block
// rides on k_agg (LAST kernel of the PREVIOUS... forbidden).
// => the memset simply stays. The only safe trim: merge gemm1 INTO
// k_fine's dispatch as extra blocks (fine: 256 blocks + gemm1: 1024
// blocks = 1280). fine reads packed/cursorG; gemm1 reads x,W1,dis -- but
// gemm1 needs dis which FINE ITSELF writes. RACE. 
// Final implemented structure: merge k_coarse and k_gemm_pre where
// gemm_pre computes h1 into fp32 scratch WITHOUT dis (truly independent),
// and k_fine's extra blocks then do the cheap scale+bf16 pack pass.
// h1 fp32 scratch = 16 MB (have room), pack pass = 16MB read + 8MB write
// streaming ~ 4 us across 1280-block dispatch. Net: 6 dispatches -> 5:
//   memset+? NO memset needed: cursorG zeroing rides as block nbk+... of
//   the MERGED coarse|gemm kernel? cursors used by coarse blocks of the
//   SAME kernel. RACE again.
// ---- Given the dependency web, the clean 5-dispatch plan is:
//   D1: k_pre    = gemm1->h1 fp32 (1024 blks) || memset cursorG (1 blk)
//        (cursorG not read by anyone in D1 -- safe)
//   D2: k_coarse (reads zeroed cursorG)
//   D3: k_fine   = CSR+dis (256 blks) || pack h1*dis->HSb1 bf16? needs dis
//        of rows in OTHER blocks. RACE. So pack rides on D4's entry: each
//        aggemm block packs... aggemm gathers RANDOM rows - needs ALL
//        packed. DEAD END.
//   => pack must be its own dispatch OR HSb1 stays fp32 (16MB table,
//      2x gather bytes - measured R3: fp32 table cost +18us/pass).
// Decision: accept 6 dispatches but make D1 = gemm1(fp32->bf16 UNSCALED
// table) || memset, and fold the *dis scaling of gathered rows* into the
// epilogue using the identity:
//   sum_s bf16(h[s])*dis[s]  !=  what we compute... per-edge scale needed.
// NOT equal. Scrap. ==> This round: keep R15 structure verbatim, single
// change: memset dispatch replaced by zero-block riding on k_gemm64s
// moved FIRST with dis-scaling REMOVED from gemm1 and APPLIED during
// k_aggemm/k_agg via per-edge dis[s] gather (+1 dword/edge, ~4MB/pass).
// Cost ~2-3us/pass; saving ~8-10us of dispatch overhead. Net predicted win.

__global__ __launch_bounds__(256) void k_gemm64u(const float* __restrict__ X,
                                                 const float* __restrict__ W,
                                                 unsigned* __restrict__ Hb,
                                                 int* __restrict__ cursorG,
                                                 int nTiles) {
    if ((int)blockIdx.x >= nTiles) {           // extra block: zero cursors
        if (threadIdx.x < 256) cursorG[threadIdx.x] = 0;
        return;
    }
    __shared__ float Ws[64 * 64];     // [k][f]
    __shared__ float XsT[64 * 68];    // [k][r]

    const int tid  = threadIdx.x;
    const int row0 = blockIdx.x * 64;

    for (int i = tid; i < 4096; i += 256) Ws[i] = W[i];
    for (int i = tid; i < 4096; i += 256) {
        int r = i >> 6, k = i & 63;
        XsT[k * 68 + r] = X[(row0 + r) * FDIM + k];
    }
    __syncthreads();

    const int tx = tid & 15;   // feature quad
    const int ty = tid >> 4;   // row quad

    float4 acc0 = {0,0,0,0}, acc1 = {0,0,0,0}, acc2 = {0,0,0,0}, acc3 = {0,0,0,0};

    #pragma unroll
    for (int k = 0; k < 64; ++k) {
        float4 wv = *(const float4*)&Ws[k * 64 + tx * 4];
        float4 xv = *(const float4*)&XsT[k * 68 + ty * 4];
        acc0.x = fmaf(xv.x, wv.x, acc0.x); acc0.y = fmaf(xv.x, wv.y, acc0.y);
        acc0.z = fmaf(xv.x, wv.z, acc0.z); acc0.w = fmaf(xv.x, wv.w, acc0.w);
        acc1.x = fmaf(xv.y, wv.x, acc1.x); acc1.y = fmaf(xv.y, wv.y, acc1.y);
        acc1.z = fmaf(xv.y, wv.z, acc1.z); acc1.w = fmaf(xv.y, wv.w, acc1.w);
        acc2.x = fmaf(xv.z, wv.x, acc2.x); acc2.y = fmaf(xv.z, wv.y, acc2.y);
        acc2.z = fmaf(xv.z, wv.z, acc2.z); acc2.w = fmaf(xv.z, wv.w, acc2.w);
        acc3.x = fmaf(xv.w, wv.x, acc3.x); acc3.y = fmaf(xv.w, wv.y, acc3.y);
        acc3.z = fmaf(xv.w, wv.z, acc3.z); acc3.w = fmaf(xv.w, wv.w, acc3.w);
    }

    uint2* H2 = (uint2*)Hb;   // row stride = 64 bf16 = 16 uint2  (UNSCALED)
    uint2 o;
    o.x = f2bf(acc0.x) | (f2bf(acc0.y) << 16);
    o.y = f2bf(acc0.z) | (f2bf(acc0.w) << 16);
    H2[(row0 + ty * 4 + 0) * 16 + tx] = o;
    o.x = f2bf(acc1.x) | (f2bf(acc1.y) << 16);
    o.y = f2bf(acc1.z) | (f2bf(acc1.w) << 16);
    H2[(row0 + ty * 4 + 1) * 16 + tx] = o;
    o.x = f2bf(acc2.x) | (f2bf(acc2.y) << 16);
    o.y = f2bf(acc2.z) | (f2bf(acc2.w) << 16);
    H2[(row0 + ty * 4 + 2) * 16 + tx] = o;
    o.x = f2bf(acc3.x) | (f2bf(acc3.y) << 16);
    o.y = f2bf(acc3.z) | (f2bf(acc3.w) << 16);
    H2[(row0 + ty * 4 + 3) * 16 + tx] = o;
}

// ======== scaled GEMM (layer-2 tail of aggemm needs dis at hand; identical to R15) ========

// ============== CSR build: fixed-capacity bucket sort ==============

__global__ __launch_bounds__(256) void k_coarse(const int* __restrict__ ei,
                                                int* __restrict__ cursorG,
                                                int* __restrict__ packed, int nE) {
    __shared__ int lh[256], gb[256], lc[256];
    int t = threadIdx.x;
    lh[t] = 0; lc[t] = 0;
    __syncthreads();
    int base = blockIdx.x * EPB;
    int bins[EPB / 256], vals[EPB / 256];
    #pragma unroll
    for (int i = 0; i < EPB / 256; ++i) {
        int e = base + i * 256 + t;
        if (e < nE) {
            int s = ei[e];
            int d = ei[nE + e];
            bins[i] = d >> 8;
            vals[i] = (s << 8) | (d & 255);
            atomicAdd(&lh[bins[i]], 1);
        } else {
            bins[i] = -1;
        }
    }
    __syncthreads();
    gb[t] = atomicAdd(&cursorG[t], lh[t]);   // global run reservation in bin t
    __syncthreads();
    #pragma unroll
    for (int i = 0; i < EPB / 256; ++i) {
        int b = bins[i];
        if (b >= 0) {
            int p = gb[b] + atomicAdd(&lc[b], 1);
            if (p < BCAP) packed[b * BCAP + p] = vals[i];
        }
    }
}

__global__ __launch_bounds__(256) void k_fine(const int* __restrict__ packed,
                                              const int* __restrict__ cursorG,
                                              float* __restrict__ dis,
                                              int* __restrict__ rowStart,
                                              unsigned short* __restrict__ lenArr,
                                              unsigned short* __restrict__ sortedSrc,
                                              int n) {
    __shared__ int cnt[256], loc[256], lc[256];
    int t = threadIdx.x;
    int b = blockIdx.x;
    int lo = b * BCAP;
    int hi = lo + cursorG[b];
    cnt[t] = 0; lc[t] = 0;
    __syncthreads();
    for (int k = lo + t; k < hi; k += 256)
        atomicAdd(&cnt[packed[k] & 255], 1);
    __syncthreads();

    int c = cnt[t];
    int node = (b << 8) + t;
    dis[node]    = rsqrtf((float)c + 1.0f);
    lenArr[node] = (unsigned short)c;

    loc[t] = c;
    __syncthreads();
    #pragma unroll
    for (int off = 1; off < 256; off <<= 1) {
        int u = (t >= off) ? loc[t - off] : 0;
        __syncthreads();
        loc[t] += u;
        __syncthreads();
    }
    int excl = loc[t] - c;
    rowStart[node] = lo + excl;
    __syncthreads();
    loc[t] = excl;
    __syncthreads();

    for (int k = lo + t; k < hi; k += 256) {
        int v = packed[k];
        int dl = v & 255;
        int p = loc[dl] + atomicAdd(&lc[dl], 1);
        sortedSrc[lo + p] = (unsigned short)(v >> 8);
    }
}

// ======== FUSED: agg1 (per-edge dis[s] scale) -> LDS -> gemm2 (scaled) -> HSb2 ========

__global__ __launch_bounds__(256) void k_aggemm(const unsigned* __restrict__ Hb1,
                                                const float* __restrict__ dis,
                                                const int* __restrict__ rowStart,
                                                const unsigned short* __restrict__ lenArr,
                                                const unsigned short* __restrict__ esrc,
                                                const float* __restrict__ bias,
                                                const float* __restrict__ W,
                                                unsigned* __restrict__ Hb2) {
    __shared__ float Ws[64 * 64];     // W2 [k][f]
    __shared__ float XsT[64 * 68];    // y1 [k][r]

    const int tid  = threadIdx.x;
    const int row0 = blockIdx.x * 64;

    for (int i = tid; i < 4096; i += 256) Ws[i] = W[i];

    const int fq = tid & 7;
    const int rr = tid >> 3;           // 0..31
    const uint4* H = (const uint4*)Hb1;
    const float4* b4 = (const float4*)bias;
    const float4 bb0 = b4[fq * 2];
    const float4 bb1 = b4[fq * 2 + 1];

    #pragma unroll
    for (int half = 0; half < 2; ++half) {
        const int r   = rr + half * 32;
        const int row = row0 + r;
        const int start = rowStart[row];
        const int end   = start + (int)lenArr[row];

        nf2 p0 = {0, 0}, p1 = {0, 0}, p2 = {0, 0}, p3 = {0, 0};
        int k = start;
        for (; k + 4 <= end; k += 4) {
            int s0 = (int)__builtin_nontemporal_load(&esrc[k]);
            int s1 = (int)__builtin_nontemporal_load(&esrc[k + 1]);
            int s2 = (int)__builtin_nontemporal_load(&esrc[k + 2]);
            int s3 = (int)__builtin_nontemporal_load(&esrc[k + 3]);
            uint4 v0 = H[s0 * 8 + fq];
            uint4 v1 = H[s1 * 8 + fq];
            uint4 v2 = H[s2 * 8 + fq];
            uint4 v3 = H[s3 * 8 + fq];
            float w0 = dis[s0], w1 = dis[s1], w2 = dis[s2], w3 = dis[s3];
            p0 += (nf2){bflo(v0.x) * w0, bfhi(v0.x) * w0};
            p1 += (nf2){bflo(v0.y) * w0, bfhi(v0.y) * w0};
            p2 += (nf2){bflo(v0.z) * w0, bfhi(v0.z) * w0};
            p3 += (nf2){bflo(v0.w) * w0, bfhi(v0.w) * w0};
            p0 += (nf2){bflo(v1.x) * w1, bfhi(v1.x) * w1};
            p1 += (nf2){bflo(v1.y) * w1, bfhi(v1.y) * w1};
            p2 += (nf2){bflo(v1.z) * w1, bfhi(v1.z) * w1};
            p3 += (nf2){bflo(v1.w) * w1, bfhi(v1.w) * w1};
            p0 += (nf2){bflo(v2.x) * w2, bfhi(v2.x) * w2};
            p1 += (nf2){bflo(v2.y) * w2, bfhi(v2.y) * w2};
            p2 += (nf2){bflo(v2.z) * w2, bfhi(v2.z) * w2};
            p3 += (nf2){bflo(v2.w) * w2, bfhi(v2.w) * w2};
            p0 += (nf2){bflo(v3.x) * w3, bfhi(v3.x) * w3};
            p1 += (nf2){bflo(v3.y) * w3, bfhi(v3.y) * w3};
            p2 += (nf2){bflo(v3.z) * w3, bfhi(v3.z) * w3};
            p3 += (nf2){bflo(v3.w) * w3, bfhi(v3.w) * w3};
        }
        for (; k < end; ++k) {
            int s0 = (int)__builtin_nontemporal_load(&esrc[k]);
            uint4 v0 = H[s0 * 8 + fq];
            float w0 = dis[s0];
            p0 += (nf2){bflo(v0.x) * w0, bfhi(v0.x) * w0};
            p1 += (nf2){bflo(v0.y) * w0, bfhi(v0.y) * w0};
            p2 += (nf2){bflo(v0.z) * w0, bfhi(v0.z) * w0};
            p3 += (nf2){bflo(v0.w) * w0, bfhi(v0.w) * w0};
        }

        uint4 sv = H[row * 8 + fq];
        float ds = dis[row];
        float* col = &XsT[(fq * 8) * 68 + r];    // k-stride 68 floats
        col[0 * 68] = fmaxf(fmaf(fmaf(bflo(sv.x), ds, p0.x), ds, bb0.x), 0.f);
        col[1 * 68] = fmaxf(fmaf(fmaf(bfhi(sv.x), ds, p0.y), ds, bb0.y), 0.f);
        col[2 * 68] = fmaxf(fmaf(fmaf(bflo(sv.y), ds, p1.x), ds, bb0.z), 0.f);
        col[3 * 68] = fmaxf(fmaf(fmaf(bfhi(sv.y), ds, p1.y), ds, bb0.w), 0.f);
        col[4 * 68] = fmaxf(fmaf(fmaf(bflo(sv.z), ds, p2.x), ds, bb1.x), 0.f);
        col[5 * 68] = fmaxf(fmaf(fmaf(bfhi(sv.z), ds, p2.y), ds, bb1.y), 0.f);
        col[6 * 68] = fmaxf(fmaf(fmaf(bflo(sv.w), ds, p3.x), ds, bb1.z), 0.f);
        col[7 * 68] = fmaxf(fmaf(fmaf(bfhi(sv.w), ds, p3.y), ds, bb1.w), 0.f);
    }
    __syncthreads();

    // ---- gemm2 on the in-LDS y1 tile (UNSCALED output table) ----
    const int tx = tid & 15;
    const int ty = tid >> 4;

    float4 acc0 = {0,0,0,0}, acc1 = {0,0,0,0}, acc2 = {0,0,0,0}, acc3 = {0,0,0,0};

    #pragma unroll
    for (int k = 0; k < 64; ++k) {
        float4 wv = *(const float4*)&Ws[k * 64 + tx * 4];
        float4 xv = *(const float4*)&XsT[k * 68 + ty * 4];
        acc0.x = fmaf(xv.x, wv.x, acc0.x); acc0.y = fmaf(xv.x, wv.y, acc0.y);
        acc0.z = fmaf(xv.x, wv.z, acc0.z); acc0.w = fmaf(xv.x, wv.w, acc0.w);
        acc1.x = fmaf(xv.y, wv.x, acc1.x); acc1.y = fmaf(xv.y, wv.y, acc1.y);
        acc1.z = fmaf(xv.y, wv.z, acc1.z); acc1.w = fmaf(xv.y, wv.w, acc1.w);
        acc2.x = fmaf(xv.z, wv.x, acc2.x); acc2.y = fmaf(xv.z, wv.y, acc2.y);
        acc2.z = fmaf(xv.z, wv.z, acc2.z); acc2.w = fmaf(xv.z, wv.w, acc2.w);
        acc3.x = fmaf(xv.w, wv.x, acc3.x); acc3.y = fmaf(xv.w, wv.y, acc3.y);
        acc3.z = fmaf(xv.w, wv.z, acc3.z); acc3.w = fmaf(xv.w, wv.w, acc3.w);
    }

    uint2* H2 = (uint2*)Hb2;
    uint2 o;
    o.x = f2bf(acc0.x) | (f2bf(acc0.y) << 16);
    o.y = f2bf(acc0.z) | (f2bf(acc0.w) << 16);
    H2[(row0 + ty * 4 + 0) * 16 + tx] = o;
    o.x = f2bf(acc1.x) | (f2bf(acc1.y) << 16);
    o.y = f2bf(acc1.z) | (f2bf(acc1.w) << 16);
    H2[(row0 + ty * 4 + 1) * 16 + tx] = o;
    o.x = f2bf(acc2.x) | (f2bf(acc2.y) << 16);
    o.y = f2bf(acc2.z) | (f2bf(acc2.w) << 16);
    H2[(row0 + ty * 4 + 2) * 16 + tx] = o;
    o.x = f2bf(acc3.x) | (f2bf(acc3.y) << 16);
    o.y = f2bf(acc3.z) | (f2bf(acc3.w) << 16);
    H2[(row0 + ty * 4 + 3) * 16 + tx] = o;
}

// ===== agg2: per-edge dis[s] scale -> out =====

__global__ __launch_bounds__(256) void k_agg(const unsigned* __restrict__ Hb,
                                             const float* __restrict__ dis,
                                             const int* __restrict__ rowStart,
                                             const unsigned short* __restrict__ lenArr,
                                             const unsigned short* __restrict__ esrc,
                                             const float* __restrict__ bias,
                                             float* __restrict__ out) {
    const int tid = threadIdx.x;
    const int fq  = tid & 7;
    const int row = blockIdx.x * 32 + (tid >> 3);

    const int start = rowStart[row];
    const int end   = start + (int)lenArr[row];

    const uint4* H = (const uint4*)Hb;

    nf2 p0 = {0, 0}, p1 = {0, 0}, p2 = {0, 0}, p3 = {0, 0};

    int k = start;
    for (; k + 4 <= end; k += 4) {
        int s0 = (int)__builtin_nontemporal_load(&esrc[k]);
        int s1 = (int)__builtin_nontemporal_load(&esrc[k + 1]);
        int s2 = (int)__builtin_nontemporal_load(&esrc[k + 2]);
        int s3 = (int)__builtin_nontemporal_load(&esrc[k + 3]);
        uint4 v0 = H[s0 * 8 + fq];
        uint4 v1 = H[s1 * 8 + fq];
        uint4 v2 = H[s2 * 8 + fq];
        uint4 v3 = H[s3 * 8 + fq];
        float w0 = dis[s0], w1 = dis[s1], w2 = dis[s2], w3 = dis[s3];
        p0 += (nf2){bflo(v0.x) * w0, bfhi(v0.x) * w0};
        p1 += (nf2){bflo(v0.y) * w0, bfhi(v0.y) * w0};
        p2 += (nf2){bflo(v0.z) * w0, bfhi(v0.z) * w0};
        p3 += (nf2){bflo(v0.w) * w0, bfhi(v0.w) * w0};
        p0 += (nf2){bflo(v1.x) * w1, bfhi(v1.x) * w1};
        p1 += (nf2){bflo(v1.y) * w1, bfhi(v1.y) * w1};
        p2 += (nf2){bflo(v1.z) * w1, bfhi(v1.z) * w1};
        p3 += (nf2){bflo(v1.w) * w1, bfhi(v1.w) * w1};
        p0 += (nf2){bflo(v2.x) * w2, bfhi(v2.x) * w2};
        p1 += (nf2){bflo(v2.y) * w2, bfhi(v2.y) * w2};
        p2 += (nf2){bflo(v2.z) * w2, bfhi(v2.z) * w2};
        p3 += (nf2){bflo(v2.w) * w2, bfhi(v2.w) * w2};
        p0 += (nf2){bflo(v3.x) * w3, bfhi(v3.x) * w3};
        p1 += (nf2){bflo(v3.y) * w3, bfhi(v3.y) * w3};
        p2 += (nf2){bflo(v3.z) * w3, bfhi(v3.z) * w3};
        p3 += (nf2){bflo(v3.w) * w3, bfhi(v3.w) * w3};
    }
    for (; k < end; ++k) {
        int s0 = (int)__builtin_nontemporal_load(&esrc[k]);
        uint4 v0 = H[s0 * 8 + fq];
        float w0 = dis[s0];
        p0 += (nf2){bflo(v0.x) * w0, bfhi(v0.x) * w0};
        p1 += (nf2){bflo(v0.y) * w0, bfhi(v0.y) * w0};
        p2 += (nf2){bflo(v0.z) * w0, bfhi(v0.z) * w0};
        p3 += (nf2){bflo(v0.w) * w0, bfhi(v0.w) * w0};
    }

    uint4 sv = H[row * 8 + fq];
    float ds = dis[row];
    const float4* b4 = (const float4*)bias;
    float4 b0 = b4[fq * 2];
    float4 b1 = b4[fq * 2 + 1];

    nf4 r0, r1;
    r0.x = fmaxf(fmaf(fmaf(bflo(sv.x), ds, p0.x), ds, b0.x), 0.f);
    r0.y = fmaxf(fmaf(fmaf(bfhi(sv.x), ds, p0.y), ds, b0.y), 0.f);
    r0.z = fmaxf(fmaf(fmaf(bflo(sv.y), ds, p1.x), ds, b0.z), 0.f);
    r0.w = fmaxf(fmaf(fmaf(bfhi(sv.y), ds, p1.y), ds, b0.w), 0.f);
    r1.x = fmaxf(fmaf(fmaf(bflo(sv.z), ds, p2.x), ds, b1.x), 0.f);
    r1.y = fmaxf(fmaf(fmaf(bfhi(sv.z), ds, p2.y), ds, b1.y), 0.f);
    r1.z = fmaxf(fmaf(fmaf(bflo(sv.w), ds, p3.x), ds, b1.z), 0.f);
    r1.w = fmaxf(fmaf(fmaf(bfhi(sv.w), ds, p3.y), ds, b1.w), 0.f);

    nf4* O = (nf4*)out;
    __builtin_nontemporal_store(r0, &O[row * 16 + fq * 2]);
    __builtin_nontemporal_store(r1, &O[row * 16 + fq * 2 + 1]);
}

// ================= launch =================

extern "C" void kernel_launch(void* const* d_in, const int* in_sizes, int n_in,
                              void* d_out, int out_size, void* d_ws, size_t ws_size,
                              hipStream_t stream) {
    const float* x  = (const float*)d_in[0];
    const int*   ei = (const int*)d_in[1];
    const float* W1 = (const float*)d_in[2];
    const float* b1 = (const float*)d_in[3];
    const float* W2 = (const float*)d_in[4];
    const float* b2 = (const float*)d_in[5];

    const int N = in_sizes[0] / FDIM;    // 65536
    const int E = in_sizes[1] / 2;       // 1048576

    char* ws = (char*)d_ws;
    float*          dis       = (float*)(ws);                    // 256 KB
    int*            rowStart  = (int*)  (ws + 262144);           // N ints
    unsigned short* lenArr    = (unsigned short*)(ws + 524288);  // N ushort
    int*            cursorG   = (int*)  (ws + 655360);           // 256 ints
    unsigned short* sortedSrc = (unsigned short*)(ws + 656384);  // 256*BCAP ushort = 3 MB
    char*           heap      = ws + 656384 + 3145728;
    int*            packed    = (int*)(heap + 8388608);          // 6 MB (after HSb1)
    unsigned*       HSb1      = (unsigned*)heap;                 // 8 MB (LIVE across whole call now)
    unsigned*       HSb2      = (unsigned*)(heap + 8388608 + 6291456);  // 8 MB

    const int nTiles = N / 64;   // 1024

    // D1: gemm1 (unscaled bf16 table) + cursorG zeroing block
    k_gemm64u<<<nTiles + 1, 256, 0, stream>>>(x, W1, HSb1, cursorG, nTiles);
    // D2, D3: CSR build + degrees
    k_coarse<<<(E + EPB - 1) / EPB, 256, 0, stream>>>(ei, cursorG, packed, E);
    k_fine  <<<256, 256, 0, stream>>>(packed, cursorG, dis, rowStart, lenArr, sortedSrc, N);
    // D4: fused agg1 + gemm2
    k_aggemm<<<nTiles, 256, 0, stream>>>(HSb1, dis, rowStart, lenArr, sortedSrc, b1, W2, HSb2);
    // D5: agg2 -> out
    k_agg   <<<N / 32, 256, 0, stream>>>(HSb2, dis, rowStart, lenArr, sortedSrc, b2, (float*)d_out);
}

// Round 17
// 117.249 us; speedup vs baseline: 1.0504x; 1.0504x over previous
//
#include <hip/hip_runtime.h>

#define FDIM 64
#define EPB  1024    // edges per block for coarse (grid = 1024 -> 4 blocks/CU)
#define BCAP 6144    // fixed bucket capacity: mean 4096, sd 64 -> +32 sd margin

typedef float nf4 __attribute__((ext_vector_type(4)));
typedef float nf2 __attribute__((ext_vector_type(2)));

// ---- bf16 helpers (manual, RNE) ----
__device__ __forceinline__ unsigned f2bf(float f) {
    unsigned u = __float_as_uint(f);
    u += 0x7fffu + ((u >> 16) & 1u);
    return u >> 16;
}
__device__ __forceinline__ float bflo(unsigned u) { return __uint_as_float(u << 16); }
__device__ __forceinline__ float bfhi(unsigned u) { return __uint_as_float(u & 0xffff0000u); }

// accumulate one gathered uint4 (8 bf16) into 4 packed-f32 pairs
#define ACC4(v) \
    p0 += (nf2){bflo((v).x), bfhi((v).x)}; p1 += (nf2){bflo((v).y), bfhi((v).y)}; \
    p2 += (nf2){bflo((v).z), bfhi((v).z)}; p3 += (nf2){bflo((v).w), bfhi((v).w)};

// ============== CSR build: fixed-capacity bucket sort ==============

__global__ __launch_bounds__(256) void k_coarse(const int* __restrict__ ei,
                                                int* __restrict__ cursorG,
                                                int* __restrict__ packed, int nE) {
    __shared__ int lh[256], gb[256], lc[256];
    int t = threadIdx.x;
    lh[t] = 0; lc[t] = 0;
    __syncthreads();
    int base = blockIdx.x * EPB;
    int bins[EPB / 256], vals[EPB / 256];
    #pragma unroll
    for (int i = 0; i < EPB / 256; ++i) {
        int e = base + i * 256 + t;
        if (e < nE) {
            int s = ei[e];
            int d = ei[nE + e];
            bins[i] = d >> 8;
            vals[i] = (s << 8) | (d & 255);
            atomicAdd(&lh[bins[i]], 1);
        } else {
            bins[i] = -1;
        }
    }
    __syncthreads();
    gb[t] = atomicAdd(&cursorG[t], lh[t]);   // global run reservation in bin t
    __syncthreads();
    #pragma unroll
    for (int i = 0; i < EPB / 256; ++i) {
        int b = bins[i];
        if (b >= 0) {
            int p = gb[b] + atomicAdd(&lc[b], 1);
            if (p < BCAP) packed[b * BCAP + p] = vals[i];
        }
    }
}

__global__ __launch_bounds__(256) void k_fine(const int* __restrict__ packed,
                                              const int* __restrict__ cursorG,
                                              float* __restrict__ dis,
                                              int* __restrict__ rowStart,
                                              unsigned short* __restrict__ lenArr,
                                              unsigned short* __restrict__ sortedSrc,
                                              int n) {
    __shared__ int cnt[256], loc[256], lc[256];
    int t = threadIdx.x;
    int b = blockIdx.x;
    int lo = b * BCAP;
    int hi = lo + cursorG[b];
    cnt[t] = 0; lc[t] = 0;
    __syncthreads();
    for (int k = lo + t; k < hi; k += 256)
        atomicAdd(&cnt[packed[k] & 255], 1);
    __syncthreads();

    int c = cnt[t];
    int node = (b << 8) + t;
    dis[node]    = rsqrtf((float)c + 1.0f);
    lenArr[node] = (unsigned short)c;

    loc[t] = c;
    __syncthreads();
    #pragma unroll
    for (int off = 1; off < 256; off <<= 1) {
        int u = (t >= off) ? loc[t - off] : 0;
        __syncthreads();
        loc[t] += u;
        __syncthreads();
    }
    int excl = loc[t] - c;
    rowStart[node] = lo + excl;
    __syncthreads();
    loc[t] = excl;
    __syncthreads();

    for (int k = lo + t; k < hi; k += 256) {
        int v = packed[k];
        int dl = v & 255;
        int p = loc[dl] + atomicAdd(&lc[dl], 1);
        sortedSrc[lo + p] = (unsigned short)(v >> 8);
    }
}

// ======== GEMM1: HSb1 = bf16( (X @ W1) * dis[row] ) ========

__global__ __launch_bounds__(256) void k_gemm64s(const float* __restrict__ X,
                                                 const float* __restrict__ W,
                                                 const float* __restrict__ dis,
                                                 unsigned* __restrict__ Hb) {
    __shared__ float Ws[64 * 64];     // [k][f]
    __shared__ float XsT[64 * 68];    // [k][r]

    const int tid  = threadIdx.x;
    const int row0 = blockIdx.x * 64;

    for (int i = tid; i < 4096; i += 256) Ws[i] = W[i];
    for (int i = tid; i < 4096; i += 256) {
        int r = i >> 6, k = i & 63;
        XsT[k * 68 + r] = X[(row0 + r) * FDIM + k];
    }
    __syncthreads();

    const int tx = tid & 15;   // feature quad
    const int ty = tid >> 4;   // row quad

    float4 acc0 = {0,0,0,0}, acc1 = {0,0,0,0}, acc2 = {0,0,0,0}, acc3 = {0,0,0,0};

    #pragma unroll
    for (int k = 0; k < 64; ++k) {
        float4 wv = *(const float4*)&Ws[k * 64 + tx * 4];
        float4 xv = *(const float4*)&XsT[k * 68 + ty * 4];
        acc0.x = fmaf(xv.x, wv.x, acc0.x); acc0.y = fmaf(xv.x, wv.y, acc0.y);
        acc0.z = fmaf(xv.x, wv.z, acc0.z); acc0.w = fmaf(xv.x, wv.w, acc0.w);
        acc1.x = fmaf(xv.y, wv.x, acc1.x); acc1.y = fmaf(xv.y, wv.y, acc1.y);
        acc1.z = fmaf(xv.y, wv.z, acc1.z); acc1.w = fmaf(xv.y, wv.w, acc1.w);
        acc2.x = fmaf(xv.z, wv.x, acc2.x); acc2.y = fmaf(xv.z, wv.y, acc2.y);
        acc2.z = fmaf(xv.z, wv.z, acc2.z); acc2.w = fmaf(xv.z, wv.w, acc2.w);
        acc3.x = fmaf(xv.w, wv.x, acc3.x); acc3.y = fmaf(xv.w, wv.y, acc3.y);
        acc3.z = fmaf(xv.w, wv.z, acc3.z); acc3.w = fmaf(xv.w, wv.w, acc3.w);
    }

    float d0 = dis[row0 + ty * 4 + 0];
    float d1 = dis[row0 + ty * 4 + 1];
    float d2 = dis[row0 + ty * 4 + 2];
    float d3 = dis[row0 + ty * 4 + 3];

    uint2* H2 = (uint2*)Hb;   // row stride = 64 bf16 = 16 uint2
    uint2 o;
    o.x = f2bf(acc0.x * d0) | (f2bf(acc0.y * d0) << 16);
    o.y = f2bf(acc0.z * d0) | (f2bf(acc0.w * d0) << 16);
    H2[(row0 + ty * 4 + 0) * 16 + tx] = o;
    o.x = f2bf(acc1.x * d1) | (f2bf(acc1.y * d1) << 16);
    o.y = f2bf(acc1.z * d1) | (f2bf(acc1.w * d1) << 16);
    H2[(row0 + ty * 4 + 1) * 16 + tx] = o;
    o.x = f2bf(acc2.x * d2) | (f2bf(acc2.y * d2) << 16);
    o.y = f2bf(acc2.z * d2) | (f2bf(acc2.w * d2) << 16);
    H2[(row0 + ty * 4 + 2) * 16 + tx] = o;
    o.x = f2bf(acc3.x * d3) | (f2bf(acc3.y * d3) << 16);
    o.y = f2bf(acc3.z * d3) | (f2bf(acc3.w * d3) << 16);
    H2[(row0 + ty * 4 + 3) * 16 + tx] = o;
}

// ======== FUSED: agg1 (into LDS, fp32) -> gemm2 -> HSb2 (8-deep gather ILP) ========

__global__ __launch_bounds__(256) void k_aggemm(const unsigned* __restrict__ Hb1,
                                                const float* __restrict__ dis,
                                                const int* __restrict__ rowStart,
                                                const unsigned short* __restrict__ lenArr,
                                                const unsigned short* __restrict__ esrc,
                                                const float* __restrict__ bias,
                                                const float* __restrict__ W,
                                                unsigned* __restrict__ Hb2) {
    __shared__ float Ws[64 * 64];     // W2 [k][f]
    __shared__ float XsT[64 * 68];    // y1 [k][r]

    const int tid  = threadIdx.x;
    const int row0 = blockIdx.x * 64;

    for (int i = tid; i < 4096; i += 256) Ws[i] = W[i];

    const int fq = tid & 7;
    const int rr = tid >> 3;           // 0..31
    const uint4* H = (const uint4*)Hb1;
    const float4* b4 = (const float4*)bias;
    const float4 bb0 = b4[fq * 2];
    const float4 bb1 = b4[fq * 2 + 1];

    #pragma unroll
    for (int half = 0; half < 2; ++half) {
        const int r   = rr + half * 32;
        const int row = row0 + r;
        const int start = rowStart[row];
        const int end   = start + (int)lenArr[row];

        nf2 p0 = {0, 0}, p1 = {0, 0}, p2 = {0, 0}, p3 = {0, 0};
        int k = start;
        for (; k + 8 <= end; k += 8) {       // 8 gathers in flight
            int s0 = (int)__builtin_nontemporal_load(&esrc[k]);
            int s1 = (int)__builtin_nontemporal_load(&esrc[k + 1]);
            int s2 = (int)__builtin_nontemporal_load(&esrc[k + 2]);
            int s3 = (int)__builtin_nontemporal_load(&esrc[k + 3]);
            int s4 = (int)__builtin_nontemporal_load(&esrc[k + 4]);
            int s5 = (int)__builtin_nontemporal_load(&esrc[k + 5]);
            int s6 = (int)__builtin_nontemporal_load(&esrc[k + 6]);
            int s7 = (int)__builtin_nontemporal_load(&esrc[k + 7]);
            uint4 v0 = H[s0 * 8 + fq];
            uint4 v1 = H[s1 * 8 + fq];
            uint4 v2 = H[s2 * 8 + fq];
            uint4 v3 = H[s3 * 8 + fq];
            uint4 v4 = H[s4 * 8 + fq];
            uint4 v5 = H[s5 * 8 + fq];
            uint4 v6 = H[s6 * 8 + fq];
            uint4 v7 = H[s7 * 8 + fq];
            ACC4(v0) ACC4(v1) ACC4(v2) ACC4(v3)
            ACC4(v4) ACC4(v5) ACC4(v6) ACC4(v7)
        }
        for (; k + 4 <= end; k += 4) {
            int s0 = (int)__builtin_nontemporal_load(&esrc[k]);
            int s1 = (int)__builtin_nontemporal_load(&esrc[k + 1]);
            int s2 = (int)__builtin_nontemporal_load(&esrc[k + 2]);
            int s3 = (int)__builtin_nontemporal_load(&esrc[k + 3]);
            uint4 v0 = H[s0 * 8 + fq];
            uint4 v1 = H[s1 * 8 + fq];
            uint4 v2 = H[s2 * 8 + fq];
            uint4 v3 = H[s3 * 8 + fq];
            ACC4(v0) ACC4(v1) ACC4(v2) ACC4(v3)
        }
        for (; k < end; ++k) {
            int s0 = (int)__builtin_nontemporal_load(&esrc[k]);
            uint4 v0 = H[s0 * 8 + fq];
            ACC4(v0)
        }

        uint4 sv = H[row * 8 + fq];
        float ds = dis[row];
        float* col = &XsT[(fq * 8) * 68 + r];    // k-stride 68 floats
        col[0 * 68] = fmaxf(fmaf(p0.x + bflo(sv.x), ds, bb0.x), 0.f);
        col[1 * 68] = fmaxf(fmaf(p0.y + bfhi(sv.x), ds, bb0.y), 0.f);
        col[2 * 68] = fmaxf(fmaf(p1.x + bflo(sv.y), ds, bb0.z), 0.f);
        col[3 * 68] = fmaxf(fmaf(p1.y + bfhi(sv.y), ds, bb0.w), 0.f);
        col[4 * 68] = fmaxf(fmaf(p2.x + bflo(sv.z), ds, bb1.x), 0.f);
        col[5 * 68] = fmaxf(fmaf(p2.y + bfhi(sv.z), ds, bb1.y), 0.f);
        col[6 * 68] = fmaxf(fmaf(p3.x + bflo(sv.w), ds, bb1.z), 0.f);
        col[7 * 68] = fmaxf(fmaf(p3.y + bfhi(sv.w), ds, bb1.w), 0.f);
    }
    __syncthreads();

    // ---- gemm2 on the in-LDS y1 tile ----
    const int tx = tid & 15;
    const int ty = tid >> 4;

    float4 acc0 = {0,0,0,0}, acc1 = {0,0,0,0}, acc2 = {0,0,0,0}, acc3 = {0,0,0,0};

    #pragma unroll
    for (int k = 0; k < 64; ++k) {
        float4 wv = *(const float4*)&Ws[k * 64 + tx * 4];
        float4 xv = *(const float4*)&XsT[k * 68 + ty * 4];
        acc0.x = fmaf(xv.x, wv.x, acc0.x); acc0.y = fmaf(xv.x, wv.y, acc0.y);
        acc0.z = fmaf(xv.x, wv.z, acc0.z); acc0.w = fmaf(xv.x, wv.w, acc0.w);
        acc1.x = fmaf(xv.y, wv.x, acc1.x); acc1.y = fmaf(xv.y, wv.y, acc1.y);
        acc1.z = fmaf(xv.y, wv.z, acc1.z); acc1.w = fmaf(xv.y, wv.w, acc1.w);
        acc2.x = fmaf(xv.z, wv.x, acc2.x); acc2.y = fmaf(xv.z, wv.y, acc2.y);
        acc2.z = fmaf(xv.z, wv.z, acc2.z); acc2.w = fmaf(xv.z, wv.w, acc2.w);
        acc3.x = fmaf(xv.w, wv.x, acc3.x); acc3.y = fmaf(xv.w, wv.y, acc3.y);
        acc3.z = fmaf(xv.w, wv.z, acc3.z); acc3.w = fmaf(xv.w, wv.w, acc3.w);
    }

    float d0 = dis[row0 + ty * 4 + 0];
    float d1 = dis[row0 + ty * 4 + 1];
    float d2 = dis[row0 + ty * 4 + 2];
    float d3 = dis[row0 + ty * 4 + 3];

    uint2* H2 = (uint2*)Hb2;
    uint2 o;
    o.x = f2bf(acc0.x * d0) | (f2bf(acc0.y * d0) << 16);
    o.y = f2bf(acc0.z * d0) | (f2bf(acc0.w * d0) << 16);
    H2[(row0 + ty * 4 + 0) * 16 + tx] = o;
    o.x = f2bf(acc1.x * d1) | (f2bf(acc1.y * d1) << 16);
    o.y = f2bf(acc1.z * d1) | (f2bf(acc1.w * d1) << 16);
    H2[(row0 + ty * 4 + 1) * 16 + tx] = o;
    o.x = f2bf(acc2.x * d2) | (f2bf(acc2.y * d2) << 16);
    o.y = f2bf(acc2.z * d2) | (f2bf(acc2.w * d2) << 16);
    H2[(row0 + ty * 4 + 2) * 16 + tx] = o;
    o.x = f2bf(acc3.x * d3) | (f2bf(acc3.y * d3) << 16);
    o.y = f2bf(acc3.z * d3) | (f2bf(acc3.w * d3) << 16);
    H2[(row0 + ty * 4 + 3) * 16 + tx] = o;
}

// ===== agg2: serial per-lane chunks -> out (8-deep gather ILP) =====

__global__ __launch_bounds__(256) void k_agg(const unsigned* __restrict__ Hb,
                                             const float* __restrict__ dis,
                                             const int* __restrict__ rowStart,
                                             const unsigned short* __restrict__ lenArr,
                                             const unsigned short* __restrict__ esrc,
                                             const float* __restrict__ bias,
                                             float* __restrict__ out) {
    const int tid = threadIdx.x;
    const int fq  = tid & 7;
    const int row = blockIdx.x * 32 + (tid >> 3);

    const int start = rowStart[row];
    const int end   = start + (int)lenArr[row];

    const uint4* H = (const uint4*)Hb;

    nf2 p0 = {0, 0}, p1 = {0, 0}, p2 = {0, 0}, p3 = {0, 0};

    int k = start;
    for (; k + 8 <= end; k += 8) {       // 8 gathers in flight
        int s0 = (int)__builtin_nontemporal_load(&esrc[k]);
        int s1 = (int)__builtin_nontemporal_load(&esrc[k + 1]);
        int s2 = (int)__builtin_nontemporal_load(&esrc[k + 2]);
        int s3 = (int)__builtin_nontemporal_load(&esrc[k + 3]);
        int s4 = (int)__builtin_nontemporal_load(&esrc[k + 4]);
        int s5 = (int)__builtin_nontemporal_load(&esrc[k + 5]);
        int s6 = (int)__builtin_nontemporal_load(&esrc[k + 6]);
        int s7 = (int)__builtin_nontemporal_load(&esrc[k + 7]);
        uint4 v0 = H[s0 * 8 + fq];
        uint4 v1 = H[s1 * 8 + fq];
        uint4 v2 = H[s2 * 8 + fq];
        uint4 v3 = H[s3 * 8 + fq];
        uint4 v4 = H[s4 * 8 + fq];
        uint4 v5 = H[s5 * 8 + fq];
        uint4 v6 = H[s6 * 8 + fq];
        uint4 v7 = H[s7 * 8 + fq];
        ACC4(v0) ACC4(v1) ACC4(v2) ACC4(v3)
        ACC4(v4) ACC4(v5) ACC4(v6) ACC4(v7)
    }
    for (; k + 4 <= end; k += 4) {
        int s0 = (int)__builtin_nontemporal_load(&esrc[k]);
        int s1 = (int)__builtin_nontemporal_load(&esrc[k + 1]);
        int s2 = (int)__builtin_nontemporal_load(&esrc[k + 2]);
        int s3 = (int)__builtin_nontemporal_load(&esrc[k + 3]);
        uint4 v0 = H[s0 * 8 + fq];
        uint4 v1 = H[s1 * 8 + fq];
        uint4 v2 = H[s2 * 8 + fq];
        uint4 v3 = H[s3 * 8 + fq];
        ACC4(v0) ACC4(v1) ACC4(v2) ACC4(v3)
    }
    for (; k < end; ++k) {
        int s0 = (int)__builtin_nontemporal_load(&esrc[k]);
        uint4 v0 = H[s0 * 8 + fq];
        ACC4(v0)
    }

    uint4 sv = H[row * 8 + fq];
    float ds = dis[row];
    const float4* b4 = (const float4*)bias;
    float4 b0 = b4[fq * 2];
    float4 b1 = b4[fq * 2 + 1];

    nf4 r0, r1;
    r0.x = fmaxf(fmaf(p0.x + bflo(sv.x), ds, b0.x), 0.f);
    r0.y = fmaxf(fmaf(p0.y + bfhi(sv.x), ds, b0.y), 0.f);
    r0.z = fmaxf(fmaf(p1.x + bflo(sv.y), ds, b0.z), 0.f);
    r0.w = fmaxf(fmaf(p1.y + bfhi(sv.y), ds, b0.w), 0.f);
    r1.x = fmaxf(fmaf(p2.x + bflo(sv.z), ds, b1.x), 0.f);
    r1.y = fmaxf(fmaf(p2.y + bfhi(sv.z), ds, b1.y), 0.f);
    r1.z = fmaxf(fmaf(p3.x + bflo(sv.w), ds, b1.z), 0.f);
    r1.w = fmaxf(fmaf(p3.y + bfhi(sv.w), ds, b1.w), 0.f);

    nf4* O = (nf4*)out;
    __builtin_nontemporal_store(r0, &O[row * 16 + fq * 2]);
    __builtin_nontemporal_store(r1, &O[row * 16 + fq * 2 + 1]);
}

// ================= launch =================

extern "C" void kernel_launch(void* const* d_in, const int* in_sizes, int n_in,
                              void* d_out, int out_size, void* d_ws, size_t ws_size,
                              hipStream_t stream) {
    const float* x  = (const float*)d_in[0];
    const int*   ei = (const int*)d_in[1];
    const float* W1 = (const float*)d_in[2];
    const float* b1 = (const float*)d_in[3];
    const float* W2 = (const float*)d_in[4];
    const float* b2 = (const float*)d_in[5];

    const int N = in_sizes[0] / FDIM;    // 65536
    const int E = in_sizes[1] / 2;       // 1048576

    char* ws = (char*)d_ws;
    float*          dis       = (float*)(ws);                    // 256 KB
    int*            rowStart  = (int*)  (ws + 262144);           // N ints
    unsigned short* lenArr    = (unsigned short*)(ws + 524288);  // N ushort
    int*            cursorG   = (int*)  (ws + 655360);           // 256 ints
    unsigned short* sortedSrc = (unsigned short*)(ws + 656384);  // 256*BCAP ushort = 3 MB
    // packed (6 MB) overlays HSb1 (8 MB): packed dead before gemm1 writes HSb1.
    char*           heap      = ws + 656384 + 3145728;
    int*            packed    = (int*)heap;                      // 6 MB
    unsigned*       HSb1      = (unsigned*)heap;                 // 8 MB
    unsigned*       HSb2      = (unsigned*)(heap + 8388608);     // 8 MB

    // ---- CSR build + degrees (shared by both layers) ----
    hipMemsetAsync(cursorG, 0, 256 * sizeof(int), stream);
    k_coarse<<<(E + EPB - 1) / EPB, 256, 0, stream>>>(ei, cursorG, packed, E);
    k_fine  <<<256, 256, 0, stream>>>(packed, cursorG, dis, rowStart, lenArr, sortedSrc, N);

    // ---- layer 1 GEMM ----
    k_gemm64s<<<N / 64, 256, 0, stream>>>(x, W1, dis, HSb1);
    // ---- FUSED layer-1 agg + layer-2 GEMM ----
    k_aggemm <<<N / 64, 256, 0, stream>>>(HSb1, dis, rowStart, lenArr, sortedSrc, b1, W2, HSb2);
    // ---- layer-2 agg -> out ----
    k_agg    <<<N / 32, 256, 0, stream>>>(HSb2, dis, rowStart, lenArr, sortedSrc, b2, (float*)d_out);
}